// Round 3
// baseline (1793.131 us; speedup 1.0000x reference)
//
#include <hip/hip_runtime.h>
#include <hip/hip_bf16.h>
#include <math.h>

// Problem constants
constexpr int N_  = 32;
constexpr int C_  = 64;
constexpr int H_  = 8;
constexpr int T_  = 128;
constexpr int V_  = 25;
constexpr int TV  = T_ * V_;         // 3200
constexpr float NTV = 102400.0f;     // 32*128*25

// Workspace layout (float offsets)
constexpr size_t OFF_PE    = 0;          // 64*128*25 = 204800
constexpr size_t OFF_MT    = 204800;     // 8*64*64 = 32768  (Mt[h][c'][c] = Wk^T Wq)
constexpr size_t OFF_P     = 237568;     // 8*64*64          (P[h][o][c] = Wao_h Wv_h)
constexpr size_t OFF_ZB    = 270336;     // 8*64             (Wao_h bv_h)
constexpr size_t OFF_MK    = 270848;     // 8*64             (Wk^T bq)
constexpr size_t OFF_MQ    = 271360;     // 8*64             (Wq^T bk)
constexpr size_t OFF_S0    = 271872;     // 8 (+pad)         (bq . bk)
constexpr size_t OFF_PROBS = 271880;     // 32*8*25*25 = 160000
constexpr size_t OFF_Y2    = 431880;     // 6553600
constexpr size_t OFF_ST1   = 6985480;    // 128 (sum, sumsq)
constexpr size_t OFF_ST2   = 6985608;    // 128
constexpr size_t OFF_AB1   = 6985736;    // 128 (a, b)
constexpr size_t OFF_AB2   = 6985864;    // 128

// ---------------------------------------------------------------------------
// Setup: pos-embed table, folded weight products, bias folds, zero BN stats
// ---------------------------------------------------------------------------
__global__ void k_setup(const float* __restrict__ Wqkv, const float* __restrict__ bqkv,
                        const float* __restrict__ Wao, float* __restrict__ ws) {
    int i = blockIdx.x * 256 + threadIdx.x;
    if (i < 204800) {
        int c = i / TV;
        int r = i % TV;                 // r = t*25+v == pos index
        float freq = expf(-(float)(2 * (c >> 1)) * (9.210340371976184f / 64.0f));
        float arg = (float)r * freq;
        ws[OFF_PE + i] = (c & 1) ? cosf(arg) : sinf(arg);
        return;
    }
    int j = i - 204800;
    if (j < 32768) { // Mt[h][cp][c] = sum_dd Wk[dd,cp]*Wq[dd,c]
        int h = j >> 12, cp = (j >> 6) & 63, c = j & 63;
        const float* wk = Wqkv + (size_t)(512 + h * 64) * 64;
        const float* wq = Wqkv + (size_t)(h * 64) * 64;
        float s = 0.f;
        for (int dd = 0; dd < 64; ++dd) s = fmaf(wk[dd * 64 + cp], wq[dd * 64 + c], s);
        ws[OFF_MT + j] = s;
        return;
    }
    j -= 32768;
    if (j < 32768) { // P[h][o][c] = sum_dd Wao[o, h*64+dd]*Wv[dd,c]
        int h = j >> 12, o = (j >> 6) & 63, c = j & 63;
        const float* wa = Wao + (size_t)o * 512 + h * 64;
        const float* wv = Wqkv + (size_t)(1024 + h * 64) * 64;
        float s = 0.f;
        for (int dd = 0; dd < 64; ++dd) s = fmaf(wa[dd], wv[dd * 64 + c], s);
        ws[OFF_P + j] = s;
        return;
    }
    j -= 32768;
    if (j < 512) { // zb[h][o]
        int h = j >> 6, o = j & 63;
        float s = 0.f;
        for (int dd = 0; dd < 64; ++dd)
            s = fmaf(Wao[(size_t)o * 512 + h * 64 + dd], bqkv[1024 + h * 64 + dd], s);
        ws[OFF_ZB + j] = s;
        return;
    }
    j -= 512;
    if (j < 512) { // mk[h][cp] = sum_dd Wk[dd,cp]*bq[dd]
        int h = j >> 6, cp = j & 63;
        float s = 0.f;
        for (int dd = 0; dd < 64; ++dd)
            s = fmaf(Wqkv[(size_t)(512 + h * 64 + dd) * 64 + cp], bqkv[h * 64 + dd], s);
        ws[OFF_MK + j] = s;
        return;
    }
    j -= 512;
    if (j < 512) { // mq[h][c] = sum_dd Wq[dd,c]*bk[dd]
        int h = j >> 6, c = j & 63;
        float s = 0.f;
        for (int dd = 0; dd < 64; ++dd)
            s = fmaf(Wqkv[(size_t)(h * 64 + dd) * 64 + c], bqkv[512 + h * 64 + dd], s);
        ws[OFF_MQ + j] = s;
        return;
    }
    j -= 512;
    if (j < 8) { // s0[h] = bq_h . bk_h
        float s = 0.f;
        for (int dd = 0; dd < 64; ++dd) s = fmaf(bqkv[j * 64 + dd], bqkv[512 + j * 64 + dd], s);
        ws[OFF_S0 + j] = s;
        return;
    }
    j -= 8;
    if (j < 256) ws[OFF_ST1 + j] = 0.f; // zero stats1+stats2
}

// ---------------------------------------------------------------------------
// Scores + probs. Block = (n,h). S[u,v] = sum_t xs_v^T M xs_u (+ bias terms).
// probs = tanh(16*S)*alpha_h + att0s_h
// LDS: 75.5 KB -> 2 blocks/CU
// ---------------------------------------------------------------------------
__global__ __launch_bounds__(256) void k_scores(const float* __restrict__ x,
                                                const float* __restrict__ alphas,
                                                const float* __restrict__ att0s,
                                                float* __restrict__ ws) {
    __shared__ float Mt[64][65];
    __shared__ float G[64][101];   // [c][t*25+v], 4 t per chunk
    __shared__ float A[64][101];   // A[cp][t*25+v] = sum_c Mt[cp][c]*G[c][..v]
    __shared__ float S[640];
    __shared__ float Rs[64][25];   // sum_t xs[c,t,v]
    int nb = blockIdx.x;
    int n = nb >> 3, h = nb & 7;
    int tid = threadIdx.x;

    for (int e = tid; e < 4096; e += 256) Mt[e >> 6][e & 63] = ws[OFF_MT + (size_t)h * 4096 + e];
    for (int e = tid; e < 625; e += 256) S[e] = 0.f;
    for (int e = tid; e < 1600; e += 256) Rs[e / 25][e % 25] = 0.f;

    const float* xb = x + (size_t)n * C_ * TV;
    const float* pe = ws + OFF_PE;
    int cp = tid & 63;
    int jg = tid >> 6;
    int j0 = jg * 25;

    for (int t0 = 0; t0 < T_; t0 += 4) {
        __syncthreads(); // protect G/A from previous-iter readers (also covers init)
        for (int e = tid; e < 6400; e += 256) {
            int c = e / 100, jj = e % 100;
            size_t g = (size_t)c * TV + t0 * 25 + jj;
            G[c][jj] = xb[g] + pe[g];
        }
        __syncthreads();
        // running sum over t for bias folds
        for (int e = tid; e < 1600; e += 256) {
            int c = e / 25, v = e % 25;
            Rs[c][v] += G[c][v] + G[c][25 + v] + G[c][50 + v] + G[c][75 + v];
        }
        // phase A: A[cp][t,v] = sum_c Mt[cp][c]*G[c][t,v]
        float acc[25];
#pragma unroll
        for (int u = 0; u < 25; ++u) acc[u] = 0.f;
        for (int c = 0; c < 64; ++c) {
            float m = Mt[cp][c];
#pragma unroll
            for (int u = 0; u < 25; ++u) acc[u] = fmaf(m, G[c][j0 + u], acc[u]);
        }
#pragma unroll
        for (int u = 0; u < 25; ++u) A[cp][j0 + u] = acc[u];
        __syncthreads();
        // phase B: S[u,v] += sum_cp sum_t G[cp][t*25+u]*A[cp][t*25+v]
        for (int task = tid; task < 625; task += 256) {
            int u = task / 25, v = task % 25;
            float s = 0.f;
            for (int c2 = 0; c2 < 64; ++c2) {
#pragma unroll
                for (int tt = 0; tt < 4; ++tt)
                    s = fmaf(G[c2][tt * 25 + u], A[c2][tt * 25 + v], s);
            }
            S[task] += s;
        }
    }
    __syncthreads();
    float alpha = alphas[h];
    float Ts0 = 128.0f * ws[OFF_S0 + h];
    const float* mk = ws + OFF_MK + h * 64;
    const float* mq = ws + OFF_MQ + h * 64;
    for (int task = tid; task < 625; task += 256) {
        int u = task / 25, v = task % 25;
        float s = S[task];
        for (int c = 0; c < 64; ++c) s += mk[c] * Rs[c][u] + mq[c] * Rs[c][v];
        s += Ts0;
        s *= 16.0f; // T/sqrt(D) = 128/8
        float p = tanhf(s) * alpha + att0s[(h * 25 + u) * 25 + v];
        ws[OFF_PROBS + (size_t)(n * 8 + h) * 625 + task] = p;
    }
}

// ---------------------------------------------------------------------------
// Fused attn-out + spatial conv + BN1 stats. Block = (n, t-chunk of 4).
// att[o,t,u] = b_ao[o] + sum_h [ sum_c P_h[o,c]*Y_h[c,t,u] + zb_h[o]*rowsum_h[u] ]
//   Y_h[c,t,u] = sum_v xs[c,t,v]*probs[h,u,v]
// y1[o,t,u] = b_sp[o] + sum_{j,c2} Wsp[o,c2,j]*att[c2,t,u+j-1]   (zero-pad u)
// LDS: 73.1 KB -> 2 blocks/CU. AT aliases Y (lifetime-disjoint).
// ---------------------------------------------------------------------------
__global__ __launch_bounds__(256) void k_att(const float* __restrict__ x,
                                             const float* __restrict__ bao,
                                             const float* __restrict__ Wsp,
                                             const float* __restrict__ bsp,
                                             float* __restrict__ y1,
                                             float* __restrict__ ws) {
    __shared__ float X[64][101];
    __shared__ float YA[64][101];  // Y during h-loop; AT afterwards
    __shared__ float Wl[64][65];
    __shared__ float PRh[640];
    __shared__ float RSUMh[32];
    __shared__ float red[8][64];
    int nb = blockIdx.x;
    int n = nb >> 5;
    int t0 = (nb & 31) * 4;
    int tid = threadIdx.x;
    const float* xb = x + (size_t)n * C_ * TV;
    const float* pe = ws + OFF_PE;

    for (int e = tid; e < 6400; e += 256) {
        int c = e / 100, jj = e % 100;
        size_t g = (size_t)c * TV + t0 * 25 + jj;
        X[c][jj] = xb[g] + pe[g];
    }
    const float* pg = ws + OFF_PROBS + (size_t)n * 8 * 625;
    int o = tid & 63;
    int tg = tid >> 6;
    int j0 = tg * 25;
    float acc[25];
#pragma unroll
    for (int u = 0; u < 25; ++u) acc[u] = bao[o];

    for (int h = 0; h < 8; ++h) {
        for (int e = tid; e < 4096; e += 256) Wl[e >> 6][e & 63] = ws[OFF_P + (size_t)h * 4096 + e];
        for (int e = tid; e < 625; e += 256) PRh[e] = pg[h * 625 + e];
        __syncthreads();  // h=0: also covers X staging
        // Y[c][t*25+u] = sum_v X[c][t*25+v]*PRh[u*25+v]
        {
            float yacc[25];
#pragma unroll
            for (int u = 0; u < 25; ++u) yacc[u] = 0.f;
            for (int v = 0; v < 25; ++v) {
                float xv = X[o][j0 + v];
#pragma unroll
                for (int u = 0; u < 25; ++u) yacc[u] = fmaf(xv, PRh[u * 25 + v], yacc[u]);
            }
#pragma unroll
            for (int u = 0; u < 25; ++u) YA[o][j0 + u] = yacc[u];
        }
        if (tid < 25) {
            float s = 0.f;
            for (int v = 0; v < 25; ++v) s += PRh[tid * 25 + v];
            RSUMh[tid] = s;
        }
        __syncthreads();
        float zbh = ws[OFF_ZB + h * 64 + o];
#pragma unroll
        for (int u = 0; u < 25; ++u) acc[u] = fmaf(zbh, RSUMh[u], acc[u]);
        for (int c = 0; c < 64; ++c) {
            float m = Wl[o][c];
#pragma unroll
            for (int u = 0; u < 25; ++u) acc[u] = fmaf(m, YA[c][j0 + u], acc[u]);
        }
        __syncthreads();
    }
#pragma unroll
    for (int u = 0; u < 25; ++u) YA[o][j0 + u] = acc[u];  // AT

    float cacc[25];
#pragma unroll
    for (int u = 0; u < 25; ++u) cacc[u] = bsp[o];

#define CONVTAP(JJ, ULO, UHI, DU)                                              \
    for (int e = tid; e < 4096; e += 256) Wl[e >> 6][e & 63] = Wsp[e * 3 + JJ]; \
    __syncthreads();                                                           \
    for (int c2 = 0; c2 < 64; ++c2) {                                          \
        float m = Wl[o][c2];                                                   \
        _Pragma("unroll")                                                      \
        for (int u = ULO; u < UHI; ++u) cacc[u] = fmaf(m, YA[c2][j0 + u + DU], cacc[u]); \
    }                                                                          \
    __syncthreads();

    CONVTAP(0, 1, 25, -1)
    CONVTAP(1, 0, 25, 0)
    CONVTAP(2, 0, 24, 1)
#undef CONVTAP

    // BN1 partial stats
    float s1 = 0.f, s2 = 0.f;
#pragma unroll
    for (int u = 0; u < 25; ++u) { s1 += cacc[u]; s2 = fmaf(cacc[u], cacc[u], s2); }
    red[tg][o] = s1;
    red[4 + tg][o] = s2;
    __syncthreads();
    if (tid < 64) {
        float ss = red[0][tid] + red[1][tid] + red[2][tid] + red[3][tid];
        float sq = red[4][tid] + red[5][tid] + red[6][tid] + red[7][tid];
        atomicAdd(&ws[OFF_ST1 + tid], ss);
        atomicAdd(&ws[OFF_ST1 + 64 + tid], sq);
    }
    float* yb = y1 + (size_t)n * C_ * TV + (size_t)o * TV + (size_t)(t0 + tg) * 25;
#pragma unroll
    for (int u = 0; u < 25; ++u) yb[u] = cacc[u];
}

// ---------------------------------------------------------------------------
// BN coefficient kernel: a = gamma*rsqrt(var+eps), b = beta - mean*a
// ---------------------------------------------------------------------------
__global__ void k_bn(const float* __restrict__ gamma, const float* __restrict__ beta,
                     float* __restrict__ ws, size_t statoff, size_t aboff) {
    int c = threadIdx.x;
    if (c < 64) {
        float s = ws[statoff + c], sq = ws[statoff + 64 + c];
        float mean = s / NTV;
        float var = sq / NTV - mean * mean;
        float a = gamma[c] / sqrtf(var + 1e-5f);
        ws[aboff + c] = a;
        ws[aboff + 64 + c] = beta[c] - mean * a;
    }
}

// ---------------------------------------------------------------------------
// Temporal conv (5x1 over T) on xs2 = relu(a1*y1+b1+x), + BN2 stats.
// Block = (n, t-chunk of 4), stages xs2 tile (t-halo 2) in LDS.
// LDS: 70.4 KB -> 2 blocks/CU
// ---------------------------------------------------------------------------
__global__ __launch_bounds__(256) void k_time(const float* __restrict__ x,
                                              const float* __restrict__ y1,
                                              const float* __restrict__ Wt,
                                              const float* __restrict__ bt,
                                              float* __restrict__ ws) {
    __shared__ float XS[64][200];   // [c][(t_local)*25+v], slices t0-2 .. t0+5
    __shared__ float Wl[64][65];
    __shared__ float ab[128];
    __shared__ float red[8][64];
    int nb = blockIdx.x;
    int n = nb >> 5;
    int t0 = (nb & 31) * 4;
    int tid = threadIdx.x;
    if (tid < 128) ab[tid] = ws[OFF_AB1 + tid];
    __syncthreads();
    const float* xb = x + (size_t)n * C_ * TV;
    const float* yb = y1 + (size_t)n * C_ * TV;
    for (int e = tid; e < 12800; e += 256) {
        int c = e / 200, s = e % 200;
        int tt = t0 - 2 + s / 25;
        float val = 0.f;
        if (tt >= 0 && tt < 128) {
            size_t idx = (size_t)c * TV + tt * 25 + (s % 25);
            val = fmaxf(fmaf(ab[c], yb[idx], ab[64 + c]) + xb[idx], 0.f);
        }
        XS[c][s] = val;
    }
    int o = tid & 63;
    int tg = tid >> 6; // local output t-slice
    float acc[25];
#pragma unroll
    for (int u = 0; u < 25; ++u) acc[u] = bt[o];
    __syncthreads();
    for (int kt = 0; kt < 5; ++kt) {
        for (int e = tid; e < 4096; e += 256) Wl[e >> 6][e & 63] = Wt[e * 5 + kt];
        __syncthreads();
        for (int c = 0; c < 64; ++c) {
            float m = Wl[o][c];
#pragma unroll
            for (int u = 0; u < 25; ++u)
                acc[u] = fmaf(m, XS[c][(tg + kt) * 25 + u], acc[u]);
        }
        __syncthreads();
    }
    float s1 = 0.f, s2 = 0.f;
#pragma unroll
    for (int u = 0; u < 25; ++u) { s1 += acc[u]; s2 = fmaf(acc[u], acc[u], s2); }
    red[tg][o] = s1;
    red[4 + tg][o] = s2;
    __syncthreads();
    if (tid < 64) {
        float ss = red[0][tid] + red[1][tid] + red[2][tid] + red[3][tid];
        float sq = red[4][tid] + red[5][tid] + red[6][tid] + red[7][tid];
        atomicAdd(&ws[OFF_ST2 + tid], ss);
        atomicAdd(&ws[OFF_ST2 + 64 + tid], sq);
    }
    float* y2b = ws + OFF_Y2 + (size_t)n * C_ * TV + (size_t)o * TV + (size_t)(t0 + tg) * 25;
#pragma unroll
    for (int u = 0; u < 25; ++u) y2b[u] = acc[u];
}

// ---------------------------------------------------------------------------
// Final: out = relu(a2*y2 + b2 + x), float4-vectorized
// ---------------------------------------------------------------------------
__global__ void k_final(const float* __restrict__ x, const float* __restrict__ ws,
                        float* __restrict__ out) {
    int i = blockIdx.x * 256 + threadIdx.x;
    if (i < 1638400) {
        const float4* y4 = (const float4*)(ws + OFF_Y2);
        const float4* x4 = (const float4*)x;
        float4 y = y4[i], xx = x4[i];
        int c = (i / 800) & 63; // 800 float4 per (n,c) row
        float a = ws[OFF_AB2 + c], b = ws[OFF_AB2 + 64 + c];
        float4 r;
        r.x = fmaxf(fmaf(a, y.x, b) + xx.x, 0.f);
        r.y = fmaxf(fmaf(a, y.y, b) + xx.y, 0.f);
        r.z = fmaxf(fmaf(a, y.z, b) + xx.z, 0.f);
        r.w = fmaxf(fmaf(a, y.w, b) + xx.w, 0.f);
        ((float4*)out)[i] = r;
    }
}

extern "C" void kernel_launch(void* const* d_in, const int* in_sizes, int n_in,
                              void* d_out, int out_size, void* d_ws, size_t ws_size,
                              hipStream_t stream) {
    const float* x      = (const float*)d_in[0];
    const float* Wqkv   = (const float*)d_in[1];
    const float* bqkv   = (const float*)d_in[2];
    const float* alphas = (const float*)d_in[3];
    const float* att0s  = (const float*)d_in[4];
    const float* Wao    = (const float*)d_in[5];
    const float* bao    = (const float*)d_in[6];
    const float* Wsp    = (const float*)d_in[7];
    const float* bsp    = (const float*)d_in[8];
    const float* Wt     = (const float*)d_in[9];
    const float* bt     = (const float*)d_in[10];
    const float* gamma  = (const float*)d_in[11];
    const float* beta   = (const float*)d_in[12];
    float* out = (float*)d_out;
    float* ws  = (float*)d_ws;
    float* y1  = out; // park pre-BN1 conv output in d_out; overwritten by k_final

    k_setup<<<dim3(1064), dim3(256), 0, stream>>>(Wqkv, bqkv, Wao, ws);
    k_scores<<<dim3(256), dim3(256), 0, stream>>>(x, alphas, att0s, ws);
    k_att<<<dim3(1024), dim3(256), 0, stream>>>(x, bao, Wsp, bsp, y1, ws);
    k_bn<<<dim3(1), dim3(64), 0, stream>>>(gamma, beta, ws, OFF_ST1, OFF_AB1);
    k_time<<<dim3(1024), dim3(256), 0, stream>>>(x, y1, Wt, bt, ws);
    k_bn<<<dim3(1), dim3(64), 0, stream>>>(gamma, beta, ws, OFF_ST2, OFF_AB2);
    k_final<<<dim3(6400), dim3(256), 0, stream>>>(x, ws, out);
}

// Round 4
// 1747.837 us; speedup vs baseline: 1.0259x; 1.0259x over previous
//
#include <hip/hip_runtime.h>
#include <hip/hip_bf16.h>
#include <math.h>

// Problem constants
constexpr int N_  = 32;
constexpr int C_  = 64;
constexpr int H_  = 8;
constexpr int T_  = 128;
constexpr int V_  = 25;
constexpr int TV  = T_ * V_;         // 3200
constexpr float NTV = 102400.0f;     // 32*128*25

// Workspace layout (float offsets)
constexpr size_t OFF_PE    = 0;          // 64*128*25 = 204800
constexpr size_t OFF_MT    = 204800;     // 8*64*64 (Mt[h][c'][c] = Wk^T Wq)
constexpr size_t OFF_P     = 237568;     // 8*64*64 (P[h][o][c] = Wao_h Wv_h)
constexpr size_t OFF_ZB    = 270336;     // 8*64    (Wao_h bv_h)
constexpr size_t OFF_MK    = 270848;     // 8*64    (Wk^T bq)
constexpr size_t OFF_MQ    = 271360;     // 8*64    (Wq^T bk)
constexpr size_t OFF_S0    = 271872;     // 8 (+pad)
constexpr size_t OFF_PROBS = 271880;     // 32*8*25*25 = 160000
constexpr size_t OFF_Y2    = 431880;     // 6553600
constexpr size_t OFF_ST1   = 6985480;    // 128 (sum, sumsq)
constexpr size_t OFF_ST2   = 6985608;    // 128
constexpr size_t OFF_AB1   = 6985736;    // 128 (a, b)
constexpr size_t OFF_AB2   = 6985864;    // 128

// ---------------------------------------------------------------------------
// Setup: pos-embed table, folded weight products, bias folds, zero BN stats
// ---------------------------------------------------------------------------
__global__ void k_setup(const float* __restrict__ Wqkv, const float* __restrict__ bqkv,
                        const float* __restrict__ Wao, float* __restrict__ ws) {
    int i = blockIdx.x * 256 + threadIdx.x;
    if (i < 204800) {
        int c = i / TV;
        int r = i % TV;                 // r = t*25+v == pos index
        float freq = expf(-(float)(2 * (c >> 1)) * (9.210340371976184f / 64.0f));
        float arg = (float)r * freq;
        ws[OFF_PE + i] = (c & 1) ? cosf(arg) : sinf(arg);
        return;
    }
    int j = i - 204800;
    if (j < 32768) { // Mt[h][cp][c] = sum_dd Wk[dd,cp]*Wq[dd,c]
        int h = j >> 12, cp = (j >> 6) & 63, c = j & 63;
        const float* wk = Wqkv + (size_t)(512 + h * 64) * 64;
        const float* wq = Wqkv + (size_t)(h * 64) * 64;
        float s = 0.f;
        for (int dd = 0; dd < 64; ++dd) s = fmaf(wk[dd * 64 + cp], wq[dd * 64 + c], s);
        ws[OFF_MT + j] = s;
        return;
    }
    j -= 32768;
    if (j < 32768) { // P[h][o][c] = sum_dd Wao[o, h*64+dd]*Wv[dd,c]
        int h = j >> 12, o = (j >> 6) & 63, c = j & 63;
        const float* wa = Wao + (size_t)o * 512 + h * 64;
        const float* wv = Wqkv + (size_t)(1024 + h * 64) * 64;
        float s = 0.f;
        for (int dd = 0; dd < 64; ++dd) s = fmaf(wa[dd], wv[dd * 64 + c], s);
        ws[OFF_P + j] = s;
        return;
    }
    j -= 32768;
    if (j < 512) { // zb[h][o]
        int h = j >> 6, o = j & 63;
        float s = 0.f;
        for (int dd = 0; dd < 64; ++dd)
            s = fmaf(Wao[(size_t)o * 512 + h * 64 + dd], bqkv[1024 + h * 64 + dd], s);
        ws[OFF_ZB + j] = s;
        return;
    }
    j -= 512;
    if (j < 512) { // mk[h][cp]
        int h = j >> 6, cp = j & 63;
        float s = 0.f;
        for (int dd = 0; dd < 64; ++dd)
            s = fmaf(Wqkv[(size_t)(512 + h * 64 + dd) * 64 + cp], bqkv[h * 64 + dd], s);
        ws[OFF_MK + j] = s;
        return;
    }
    j -= 512;
    if (j < 512) { // mq[h][c]
        int h = j >> 6, c = j & 63;
        float s = 0.f;
        for (int dd = 0; dd < 64; ++dd)
            s = fmaf(Wqkv[(size_t)(h * 64 + dd) * 64 + c], bqkv[512 + h * 64 + dd], s);
        ws[OFF_MQ + j] = s;
        return;
    }
    j -= 512;
    if (j < 8) { // s0[h] = bq_h . bk_h
        float s = 0.f;
        for (int dd = 0; dd < 64; ++dd) s = fmaf(bqkv[j * 64 + dd], bqkv[512 + j * 64 + dd], s);
        ws[OFF_S0 + j] = s;
        return;
    }
    j -= 8;
    if (j < 256) ws[OFF_ST1 + j] = 0.f; // zero stats1+stats2
}

// ---------------------------------------------------------------------------
// Scores + probs. Block = (n,h). Phase A as before; phase B retiled:
// thread = (v, c-slice of 8) keeps S-partials for all 25 u in registers
// across all t-chunks; single LDS-atomic combine at end.
// ---------------------------------------------------------------------------
__global__ __launch_bounds__(256) void k_scores(const float* __restrict__ x,
                                                const float* __restrict__ alphas,
                                                const float* __restrict__ att0s,
                                                float* __restrict__ ws) {
    __shared__ float Mt[64][65];
    __shared__ float G[64][101];   // [c][tt*25+v], 4 t per chunk
    __shared__ float A[64][101];   // A[cp][tt*25+v] = sum_c Mt[cp][c]*G[c][..]
    __shared__ float S[640];
    __shared__ float Rs[64][25];   // sum_t xs[c,t,v]
    int nb = blockIdx.x;
    int n = nb >> 3, h = nb & 7;
    int tid = threadIdx.x;

    for (int e = tid; e < 4096; e += 256) Mt[e >> 6][e & 63] = ws[OFF_MT + (size_t)h * 4096 + e];
    for (int e = tid; e < 640; e += 256) S[e] = 0.f;
    for (int e = tid; e < 1600; e += 256) Rs[e / 25][e % 25] = 0.f;

    const float* xb = x + (size_t)n * C_ * TV;
    const float* pe = ws + OFF_PE;
    int cp = tid & 63;
    int jg = tid >> 6;
    int j0 = jg * 25;
    int vB = tid % 25;          // phase-B role (tid < 200)
    int c0B = (tid / 25) * 8;
    float accB[25];
#pragma unroll
    for (int u = 0; u < 25; ++u) accB[u] = 0.f;

    for (int t0 = 0; t0 < T_; t0 += 4) {
        __syncthreads(); // protect G/A from previous-iter phase-B readers
        for (int e = tid; e < 6400; e += 256) {
            int c = e / 100, jj = e % 100;
            size_t g = (size_t)c * TV + t0 * 25 + jj;
            G[c][jj] = xb[g] + pe[g];
        }
        __syncthreads();
        // running sum over t for bias folds
        for (int e = tid; e < 1600; e += 256) {
            int c = e / 25, v = e % 25;
            Rs[c][v] += G[c][v] + G[c][25 + v] + G[c][50 + v] + G[c][75 + v];
        }
        // phase A: A[cp][tt,v] = sum_c Mt[cp][c]*G[c][tt,v]
        float acc[25];
#pragma unroll
        for (int u = 0; u < 25; ++u) acc[u] = 0.f;
        for (int c = 0; c < 64; ++c) {
            float m = Mt[cp][c];
#pragma unroll
            for (int u = 0; u < 25; ++u) acc[u] = fmaf(m, G[c][j0 + u], acc[u]);
        }
#pragma unroll
        for (int u = 0; u < 25; ++u) A[cp][j0 + u] = acc[u];
        __syncthreads();
        // phase B: accB[u] += sum_{c in slice} sum_tt G[c][tt*25+u]*A[c][tt*25+vB]
        if (tid < 200) {
            for (int c = c0B; c < c0B + 8; ++c) {
#pragma unroll
                for (int tt = 0; tt < 4; ++tt) {
                    float av = A[c][tt * 25 + vB];
#pragma unroll
                    for (int u = 0; u < 25; ++u)
                        accB[u] = fmaf(G[c][tt * 25 + u], av, accB[u]);
                }
            }
        }
    }
    if (tid < 200) {
#pragma unroll
        for (int u = 0; u < 25; ++u) atomicAdd(&S[u * 25 + vB], accB[u]);
    }
    __syncthreads();
    float alpha = alphas[h];
    float Ts0 = 128.0f * ws[OFF_S0 + h];
    const float* mk = ws + OFF_MK + h * 64;
    const float* mq = ws + OFF_MQ + h * 64;
    for (int task = tid; task < 625; task += 256) {
        int u = task / 25, v = task % 25;
        float s = S[task];
        for (int c = 0; c < 64; ++c) s += mk[c] * Rs[c][u] + mq[c] * Rs[c][v];
        s += Ts0;
        s *= 16.0f; // T/sqrt(D) = 128/8
        float p = tanhf(s) * alpha + att0s[(h * 25 + u) * 25 + v];
        ws[OFF_PROBS + (size_t)(n * 8 + h) * 625 + task] = p;
    }
}

// ---------------------------------------------------------------------------
// Fused attn-out + spatial conv + BN1 stats.  Block = (n, t-chunk of 8).
// Z-reformulation: att[o,t,u] = sum_v (P_h · xs)[o,t,v] * probs_h[u,v]
//   Z = P_h·X computed into REGISTERS (2 o-rows per thread), zb folded as
//   Z += zb (since sum_v (Z+zb)*probs = sum Z*probs + zb*rowsum(probs)).
// Then spatial conv from LDS att tile (aliased over X) + BN1 stats.
// LDS 74.5 KB -> 2 blocks/CU.
// ---------------------------------------------------------------------------
__global__ __launch_bounds__(256) void k_att(const float* __restrict__ x,
                                             const float* __restrict__ bao,
                                             const float* __restrict__ Wsp,
                                             const float* __restrict__ bsp,
                                             float* __restrict__ y1,
                                             float* __restrict__ ws) {
    __shared__ float XA[64][201];   // X (xs tile) during h-loop; AT after
    __shared__ float WT[64][64];    // Pt[c][o] per h; conv-tap W^T during conv
    __shared__ float PR[640];
    __shared__ float red[2][8][64];
    int nb = blockIdx.x;
    int n = nb >> 4;
    int tc = nb & 15;               // t-chunk of 8
    int tid = threadIdx.x;
    int og = tid & 31, o0 = og * 2; // 2 output channels per thread
    int tl = tid >> 5;              // 0..7 local t
    int jb = tl * 25;

    const float* xb = x + (size_t)n * C_ * TV + tc * 200;
    const float* pe = ws + OFF_PE + tc * 200;
    for (int e = tid; e < 12800; e += 256) {
        int c = e / 200, jj = e % 200;
        XA[c][jj] = xb[(size_t)c * TV + jj] + pe[(size_t)c * TV + jj];
    }
    const float* pg = ws + OFF_PROBS + (size_t)n * 8 * 625;
    float acc0[25], acc1[25];
    float b0 = bao[o0], b1 = bao[o0 + 1];
#pragma unroll
    for (int u = 0; u < 25; ++u) { acc0[u] = b0; acc1[u] = b1; }

    for (int h = 0; h < 8; ++h) {
        __syncthreads(); // protect WT/PR from prev readers (h=0: covers X staging)
        for (int e = tid; e < 4096; e += 256)
            WT[e >> 6][e & 63] = ws[OFF_P + (size_t)h * 4096 + (size_t)(e & 63) * 64 + (e >> 6)];
        for (int e = tid; e < 625; e += 256) PR[e] = pg[h * 625 + e];
        __syncthreads();
        // phase 1: Z[i][v] = sum_c P[o0+i][c] * X[c][tl,v]   (registers)
        float z0[25], z1[25];
#pragma unroll
        for (int v = 0; v < 25; ++v) { z0[v] = 0.f; z1[v] = 0.f; }
        for (int c = 0; c < 64; ++c) {
            float p0 = WT[c][o0], p1 = WT[c][o0 + 1];
#pragma unroll
            for (int v = 0; v < 25; ++v) {
                float xv = XA[c][jb + v];
                z0[v] = fmaf(p0, xv, z0[v]);
                z1[v] = fmaf(p1, xv, z1[v]);
            }
        }
        float zb0 = ws[OFF_ZB + h * 64 + o0], zb1 = ws[OFF_ZB + h * 64 + o0 + 1];
#pragma unroll
        for (int v = 0; v < 25; ++v) { z0[v] += zb0; z1[v] += zb1; }
        // phase 2: acc[i][u] += sum_v Z[i][v] * PR[u*25+v]   (in-register)
        for (int u = 0; u < 25; ++u) {
            const float* pr = &PR[u * 25];
            float a0 = acc0[u], a1 = acc1[u];
#pragma unroll
            for (int v = 0; v < 25; ++v) {
                float p = pr[v];
                a0 = fmaf(z0[v], p, a0);
                a1 = fmaf(z1[v], p, a1);
            }
            acc0[u] = a0; acc1[u] = a1;
        }
    }
    __syncthreads(); // phase-1 h=7 readers of XA done -> overwrite with AT
#pragma unroll
    for (int u = 0; u < 25; ++u) {
        XA[o0][jb + u] = acc0[u];
        XA[o0 + 1][jb + u] = acc1[u];
    }

    // spatial conv 1x3 over u (zero-pad)
    float ca0[25], ca1[25];
    float s0 = bsp[o0], s1_ = bsp[o0 + 1];
#pragma unroll
    for (int u = 0; u < 25; ++u) { ca0[u] = s0; ca1[u] = s1_; }
    for (int j = 0; j < 3; ++j) {
        __syncthreads(); // j=0: AT visible; j>0: prev-tap readers done
        for (int e = tid; e < 4096; e += 256)
            WT[e >> 6][e & 63] = Wsp[(size_t)(e & 63) * 192 + (size_t)(e >> 6) * 3 + j];
        __syncthreads();
        int ulo = (j == 0) ? 1 : 0, uhi = (j == 2) ? 24 : 25, du = j - 1;
        for (int c2 = 0; c2 < 64; ++c2) {
            float w0 = WT[c2][o0], w1 = WT[c2][o0 + 1];
            for (int u = ulo; u < uhi; ++u) {
                float av = XA[c2][jb + u + du];
                ca0[u] = fmaf(w0, av, ca0[u]);
                ca1[u] = fmaf(w1, av, ca1[u]);
            }
        }
    }

    // BN1 partial stats
    float p1 = 0.f, p2 = 0.f, q1 = 0.f, q2 = 0.f;
#pragma unroll
    for (int u = 0; u < 25; ++u) {
        p1 += ca0[u]; p2 = fmaf(ca0[u], ca0[u], p2);
        q1 += ca1[u]; q2 = fmaf(ca1[u], ca1[u], q2);
    }
    red[0][tl][o0] = p1; red[0][tl][o0 + 1] = q1;
    red[1][tl][o0] = p2; red[1][tl][o0 + 1] = q2;
    __syncthreads();
    if (tid < 64) {
        float ss = 0.f, sq = 0.f;
        for (int t2 = 0; t2 < 8; ++t2) { ss += red[0][t2][tid]; sq += red[1][t2][tid]; }
        atomicAdd(&ws[OFF_ST1 + tid], ss);
        atomicAdd(&ws[OFF_ST1 + 64 + tid], sq);
    }
    float* yb = y1 + (size_t)n * C_ * TV + (size_t)o0 * TV + (size_t)(tc * 8 + tl) * 25;
#pragma unroll
    for (int u = 0; u < 25; ++u) { yb[u] = ca0[u]; yb[TV + u] = ca1[u]; }
}

// ---------------------------------------------------------------------------
// BN coefficient kernel: a = gamma*rsqrt(var+eps), b = beta - mean*a
// ---------------------------------------------------------------------------
__global__ void k_bn(const float* __restrict__ gamma, const float* __restrict__ beta,
                     float* __restrict__ ws, size_t statoff, size_t aboff) {
    int c = threadIdx.x;
    if (c < 64) {
        float s = ws[statoff + c], sq = ws[statoff + 64 + c];
        float mean = s / NTV;
        float var = sq / NTV - mean * mean;
        float a = gamma[c] / sqrtf(var + 1e-5f);
        ws[aboff + c] = a;
        ws[aboff + 64 + c] = beta[c] - mean * a;
    }
}

// ---------------------------------------------------------------------------
// Temporal conv (5x1 over T) on xs2 = relu(a1*y1+b1+x), + BN2 stats.
// Block = (n, t-chunk of 4), xs2 tile (t-halo 2) in LDS, W^T tile per tap.
// LDS 70.4 KB -> 2 blocks/CU.
// ---------------------------------------------------------------------------
__global__ __launch_bounds__(256) void k_time(const float* __restrict__ x,
                                              const float* __restrict__ y1,
                                              const float* __restrict__ Wt,
                                              const float* __restrict__ bt,
                                              float* __restrict__ ws) {
    __shared__ float XS[64][201];   // [c][s], s = (t_local)*25+v, slices t0-2..t0+5
    __shared__ float WT[64][64];    // Wt tap transposed [c][o]
    __shared__ float ab[128];
    __shared__ float red[2][4][64];
    int nb = blockIdx.x;
    int n = nb >> 5;
    int t0 = (nb & 31) * 4;
    int tid = threadIdx.x;
    if (tid < 128) ab[tid] = ws[OFF_AB1 + tid];
    __syncthreads();
    const float* xb = x + (size_t)n * C_ * TV;
    const float* yb = y1 + (size_t)n * C_ * TV;
    for (int e = tid; e < 12800; e += 256) {
        int c = e / 200, s = e % 200;
        int tt = t0 - 2 + s / 25;
        float val = 0.f;
        if (tt >= 0 && tt < 128) {
            size_t idx = (size_t)c * TV + tt * 25 + (s % 25);
            val = fmaxf(fmaf(ab[c], yb[idx], ab[64 + c]) + xb[idx], 0.f);
        }
        XS[c][s] = val;
    }
    int o = tid & 63;
    int tl = tid >> 6; // local output t-slice 0..3
    float acc[25];
    float bo = bt[o];
#pragma unroll
    for (int u = 0; u < 25; ++u) acc[u] = bo;
    for (int kt = 0; kt < 5; ++kt) {
        __syncthreads(); // kt=0: staging done; kt>0: prev-tap WT readers done
        for (int e = tid; e < 4096; e += 256)
            WT[e >> 6][e & 63] = Wt[(size_t)(e & 63) * 320 + (size_t)(e >> 6) * 5 + kt];
        __syncthreads();
        for (int c = 0; c < 64; ++c) {
            float m = WT[c][o];
#pragma unroll
            for (int u = 0; u < 25; ++u)
                acc[u] = fmaf(m, XS[c][(tl + kt) * 25 + u], acc[u]);
        }
    }
    float s1 = 0.f, s2 = 0.f;
#pragma unroll
    for (int u = 0; u < 25; ++u) { s1 += acc[u]; s2 = fmaf(acc[u], acc[u], s2); }
    red[0][tl][o] = s1;
    red[1][tl][o] = s2;
    __syncthreads();
    if (tid < 64) {
        float ss = red[0][0][tid] + red[0][1][tid] + red[0][2][tid] + red[0][3][tid];
        float sq = red[1][0][tid] + red[1][1][tid] + red[1][2][tid] + red[1][3][tid];
        atomicAdd(&ws[OFF_ST2 + tid], ss);
        atomicAdd(&ws[OFF_ST2 + 64 + tid], sq);
    }
    float* y2b = ws + OFF_Y2 + (size_t)n * C_ * TV + (size_t)o * TV + (size_t)(t0 + tl) * 25;
#pragma unroll
    for (int u = 0; u < 25; ++u) y2b[u] = acc[u];
}

// ---------------------------------------------------------------------------
// Final: out = relu(a2*y2 + b2 + x), float4-vectorized
// ---------------------------------------------------------------------------
__global__ void k_final(const float* __restrict__ x, const float* __restrict__ ws,
                        float* __restrict__ out) {
    int i = blockIdx.x * 256 + threadIdx.x;
    if (i < 1638400) {
        const float4* y4 = (const float4*)(ws + OFF_Y2);
        const float4* x4 = (const float4*)x;
        float4 y = y4[i], xx = x4[i];
        int c = (i / 800) & 63; // 800 float4 per (n,c) row
        float a = ws[OFF_AB2 + c], b = ws[OFF_AB2 + 64 + c];
        float4 r;
        r.x = fmaxf(fmaf(a, y.x, b) + xx.x, 0.f);
        r.y = fmaxf(fmaf(a, y.y, b) + xx.y, 0.f);
        r.z = fmaxf(fmaf(a, y.z, b) + xx.z, 0.f);
        r.w = fmaxf(fmaf(a, y.w, b) + xx.w, 0.f);
        ((float4*)out)[i] = r;
    }
}

extern "C" void kernel_launch(void* const* d_in, const int* in_sizes, int n_in,
                              void* d_out, int out_size, void* d_ws, size_t ws_size,
                              hipStream_t stream) {
    const float* x      = (const float*)d_in[0];
    const float* Wqkv   = (const float*)d_in[1];
    const float* bqkv   = (const float*)d_in[2];
    const float* alphas = (const float*)d_in[3];
    const float* att0s  = (const float*)d_in[4];
    const float* Wao    = (const float*)d_in[5];
    const float* bao    = (const float*)d_in[6];
    const float* Wsp    = (const float*)d_in[7];
    const float* bsp    = (const float*)d_in[8];
    const float* Wt     = (const float*)d_in[9];
    const float* bt     = (const float*)d_in[10];
    const float* gamma  = (const float*)d_in[11];
    const float* beta   = (const float*)d_in[12];
    float* out = (float*)d_out;
    float* ws  = (float*)d_ws;
    float* y1  = out; // park pre-BN1 conv output in d_out; overwritten by k_final

    k_setup<<<dim3(1064), dim3(256), 0, stream>>>(Wqkv, bqkv, Wao, ws);
    k_scores<<<dim3(256), dim3(256), 0, stream>>>(x, alphas, att0s, ws);
    k_att<<<dim3(512), dim3(256), 0, stream>>>(x, bao, Wsp, bsp, y1, ws);
    k_bn<<<dim3(1), dim3(64), 0, stream>>>(gamma, beta, ws, OFF_ST1, OFF_AB1);
    k_time<<<dim3(1024), dim3(256), 0, stream>>>(x, y1, Wt, bt, ws);
    k_bn<<<dim3(1), dim3(64), 0, stream>>>(gamma, beta, ws, OFF_ST2, OFF_AB2);
    k_final<<<dim3(6400), dim3(256), 0, stream>>>(x, ws, out);
}

// Round 6
// 840.596 us; speedup vs baseline: 2.1332x; 2.0793x over previous
//
#include <hip/hip_runtime.h>
#include <hip/hip_bf16.h>
#include <math.h>

// Problem constants
constexpr int N_  = 32;
constexpr int C_  = 64;
constexpr int T_  = 128;
constexpr int V_  = 25;
constexpr int TV  = T_ * V_;         // 3200
constexpr float NTV = 102400.0f;     // 32*128*25

// Workspace layout (float offsets)
constexpr size_t OFF_MT    = 0;        // 8*64*64  MtT[h][c][cp] = (Wk^T Wq)[cp][c]
constexpr size_t OFF_P     = 32768;    // 8*64*64  PT[h][c][o]  = (Wao_h Wv_h)[o][c]
constexpr size_t OFF_ZB    = 65536;    // 8*64     Wao_h bv_h
constexpr size_t OFF_MK    = 66048;    // 8*64     Wk^T bq
constexpr size_t OFF_MQ    = 66560;    // 8*64     Wq^T bk
constexpr size_t OFF_S0    = 67072;    // 8 (pad 64)
constexpr size_t OFF_WSP   = 67136;    // 3*64*64  WspT[tap][c][o]
constexpr size_t OFF_WT    = 79424;    // 5*64*64  WtT[kt][c][o]
constexpr size_t OFF_SG    = 99904;    // 256*625  partial scores
constexpr size_t OFF_RU    = 259904;   // 256*25
constexpr size_t OFF_RV    = 266304;   // 256*25
constexpr size_t OFF_PROBS = 272704;   // 256*625
constexpr size_t OFF_ST1   = 432704;   // 128 (sum, sumsq)
constexpr size_t OFF_ST2   = 432832;   // 128
constexpr size_t OFF_AB1   = 432960;   // 128 (a, b)
constexpr size_t OFF_AB2   = 433088;   // 128
constexpr size_t OFF_XS    = 433216;   // 6,553,600 (x+pe; later reused as Y2)
constexpr size_t OFF_Y2    = OFF_XS;

// Load 25 consecutive floats from a 16B-aligned base via float4
#define LOAD25(dst, base)                                                     \
  { const float4* _p4 = (const float4*)(base);                                \
    float4 _a = _p4[0], _b = _p4[1], _c = _p4[2], _d = _p4[3], _e = _p4[4],   \
           _f = _p4[5];                                                       \
    dst[0]=_a.x; dst[1]=_a.y; dst[2]=_a.z; dst[3]=_a.w;                       \
    dst[4]=_b.x; dst[5]=_b.y; dst[6]=_b.z; dst[7]=_b.w;                       \
    dst[8]=_c.x; dst[9]=_c.y; dst[10]=_c.z; dst[11]=_c.w;                     \
    dst[12]=_d.x; dst[13]=_d.y; dst[14]=_d.z; dst[15]=_d.w;                   \
    dst[16]=_e.x; dst[17]=_e.y; dst[18]=_e.z; dst[19]=_e.w;                   \
    dst[20]=_f.x; dst[21]=_f.y; dst[22]=_f.z; dst[23]=_f.w;                   \
    dst[24]=((const float*)(base))[24]; }

#define STORE25(base, src)                                                    \
  { float4* _p4 = (float4*)(base);                                           \
    _p4[0] = make_float4(src[0],src[1],src[2],src[3]);                        \
    _p4[1] = make_float4(src[4],src[5],src[6],src[7]);                        \
    _p4[2] = make_float4(src[8],src[9],src[10],src[11]);                      \
    _p4[3] = make_float4(src[12],src[13],src[14],src[15]);                    \
    _p4[4] = make_float4(src[16],src[17],src[18],src[19]);                    \
    _p4[5] = make_float4(src[20],src[21],src[22],src[23]);                    \
    ((float*)(base))[24] = src[24]; }

// ---------------------------------------------------------------------------
// XS = x + pos_embed, float4-vectorized, fast trig (error ~1e-4 << tolerance)
// ---------------------------------------------------------------------------
__global__ void k_xs(const float* __restrict__ x, float* __restrict__ ws) {
    int i4 = blockIdx.x * 256 + threadIdx.x;        // over 1,638,400 float4s
    int row = i4 / 800;                              // n*64 + c
    int q = i4 % 800;
    int c = row & 63;
    int r0 = q * 4;                                  // pos index t*25+v
    float f = __expf(-(float)(2 * (c >> 1)) * 0.14391156816875288f); // ln(1e4)/64
    float4 xv = ((const float4*)x)[i4];
    float a0 = r0 * f, a1 = (r0 + 1) * f, a2 = (r0 + 2) * f, a3 = (r0 + 3) * f;
    float4 r;
    if (c & 1) {
        r.x = xv.x + __cosf(a0); r.y = xv.y + __cosf(a1);
        r.z = xv.z + __cosf(a2); r.w = xv.w + __cosf(a3);
    } else {
        r.x = xv.x + __sinf(a0); r.y = xv.y + __sinf(a1);
        r.z = xv.z + __sinf(a2); r.w = xv.w + __sinf(a3);
    }
    ((float4*)(ws + OFF_XS))[i4] = r;
}

// ---------------------------------------------------------------------------
// Setup: folded weight products (pre-transposed for linear LDS staging)
// ---------------------------------------------------------------------------
__global__ void k_setup(const float* __restrict__ Wqkv, const float* __restrict__ bqkv,
                        const float* __restrict__ Wao, const float* __restrict__ Wsp,
                        const float* __restrict__ Wt, float* __restrict__ ws) {
    int i = blockIdx.x * 256 + threadIdx.x;
    if (i < 32768) { // MtT[h][c][cp] = sum_dd Wk[dd,cp]*Wq[dd,c]
        int h = i >> 12, c = (i >> 6) & 63, cp = i & 63;
        const float* wk = Wqkv + (size_t)(512 + h * 64) * 64;
        const float* wq = Wqkv + (size_t)(h * 64) * 64;
        float s = 0.f;
        for (int dd = 0; dd < 64; ++dd) s = fmaf(wk[dd * 64 + cp], wq[dd * 64 + c], s);
        ws[OFF_MT + i] = s;
        return;
    }
    int j = i - 32768;
    if (j < 32768) { // PT[h][c][o] = sum_dd Wao[o, h*64+dd]*Wv[dd,c]
        int h = j >> 12, c = (j >> 6) & 63, o = j & 63;
        const float* wa = Wao + (size_t)o * 512 + h * 64;
        const float* wv = Wqkv + (size_t)(1024 + h * 64) * 64;
        float s = 0.f;
        for (int dd = 0; dd < 64; ++dd) s = fmaf(wa[dd], wv[dd * 64 + c], s);
        ws[OFF_P + j] = s;
        return;
    }
    j -= 32768;
    if (j < 512) { // zb[h][o]
        int h = j >> 6, o = j & 63;
        float s = 0.f;
        for (int dd = 0; dd < 64; ++dd)
            s = fmaf(Wao[(size_t)o * 512 + h * 64 + dd], bqkv[1024 + h * 64 + dd], s);
        ws[OFF_ZB + j] = s;
        return;
    }
    j -= 512;
    if (j < 512) { // mk[h][cp]
        int h = j >> 6, cp = j & 63;
        float s = 0.f;
        for (int dd = 0; dd < 64; ++dd)
            s = fmaf(Wqkv[(size_t)(512 + h * 64 + dd) * 64 + cp], bqkv[h * 64 + dd], s);
        ws[OFF_MK + j] = s;
        return;
    }
    j -= 512;
    if (j < 512) { // mq[h][c]
        int h = j >> 6, c = j & 63;
        float s = 0.f;
        for (int dd = 0; dd < 64; ++dd)
            s = fmaf(Wqkv[(size_t)(h * 64 + dd) * 64 + c], bqkv[512 + h * 64 + dd], s);
        ws[OFF_MQ + j] = s;
        return;
    }
    j -= 512;
    if (j < 8) { // s0[h] = bq_h . bk_h
        float s = 0.f;
        for (int dd = 0; dd < 64; ++dd) s = fmaf(bqkv[j * 64 + dd], bqkv[512 + j * 64 + dd], s);
        ws[OFF_S0 + j] = s;
        return;
    }
    j -= 8;
    if (j < 12288) { // WspT[tap][c][o]
        int tap = j >> 12, rest = j & 4095, c = rest >> 6, o = rest & 63;
        ws[OFF_WSP + j] = Wsp[(size_t)o * 192 + c * 3 + tap];
        return;
    }
    j -= 12288;
    if (j < 20480) { // WtT[kt][c][o]
        int kt = j >> 12, rest = j & 4095, c = rest >> 6, o = rest & 63;
        ws[OFF_WT + j] = Wt[(size_t)o * 320 + c * 5 + kt];
        return;
    }
}

// ---------------------------------------------------------------------------
// Scores partials. Block = (n, h, t-quarter of 32). Vector-row LDS layout.
// S[u,v] += sum_{c,t} G[c,t,u]*A[c,t,v], A = Mt·G. Atomic combine to ws.
// LDS 78.3 KB -> 2 blocks/CU.
// ---------------------------------------------------------------------------
__global__ __launch_bounds__(256) void k_scores(float* __restrict__ ws) {
    __shared__ float Mt[64][64];      // [c][cp]
    __shared__ float G[4][64][28];    // [tt][c][v]
    __shared__ float A[4][64][28];
    __shared__ float Rs[64][25];
    int nb = blockIdx.x;              // 1024 = 32n x 8h x 4tq
    int n = nb >> 5, h = (nb >> 2) & 7, tq = nb & 3;
    int tid = threadIdx.x;
    for (int e = tid; e < 4096; e += 256) Mt[e >> 6][e & 63] = ws[OFF_MT + (size_t)h * 4096 + e];
    for (int e = tid; e < 1600; e += 256) Rs[e / 25][e % 25] = 0.f;
    const float4* xs4 = (const float4*)(ws + OFF_XS + (size_t)n * 64 * 3200);
    int cp = tid & 63;
    int tt = tid >> 6;
    int vB = tid % 25, c0B = (tid / 25) * 8;    // phase-B role (tid < 200)
    float accB[25];
#pragma unroll
    for (int u = 0; u < 25; ++u) accB[u] = 0.f;

    for (int ch = 0; ch < 8; ++ch) {
        int t0 = tq * 32 + ch * 4;
        __syncthreads(); // prev phase-B readers of G/A done
        for (int e4 = tid; e4 < 1600; e4 += 256) {
            int c = e4 / 25, q = e4 % 25;
            float4 fv = xs4[c * 800 + ((t0 * 25) >> 2) + q];
            int jj = q * 4;
            G[jj / 25][c][jj % 25] = fv.x;
            G[(jj + 1) / 25][c][(jj + 1) % 25] = fv.y;
            G[(jj + 2) / 25][c][(jj + 2) % 25] = fv.z;
            G[(jj + 3) / 25][c][(jj + 3) % 25] = fv.w;
        }
        __syncthreads();
        for (int e = tid; e < 1600; e += 256) {
            int c = e / 25, v = e % 25;
            Rs[c][v] += G[0][c][v] + G[1][c][v] + G[2][c][v] + G[3][c][v];
        }
        // phase A: A[tt][cp][v] = sum_c Mt[c][cp]*G[tt][c][v]
        float acc[25];
#pragma unroll
        for (int u = 0; u < 25; ++u) acc[u] = 0.f;
        for (int c = 0; c < 64; ++c) {
            float m = Mt[c][cp];
            float gx[25];
            LOAD25(gx, G[tt][c]);
#pragma unroll
            for (int u = 0; u < 25; ++u) acc[u] = fmaf(m, gx[u], acc[u]);
        }
        STORE25(A[tt][cp], acc);
        __syncthreads();
        // phase B: accB[u] += sum_{c in slice, tt} G[tt][c][u]*A[tt][c][vB]
        if (tid < 200) {
            for (int ci = 0; ci < 8; ++ci) {
                int c = c0B + ci;
#pragma unroll
                for (int t2 = 0; t2 < 4; ++t2) {
                    float av = A[t2][c][vB];
                    float gx[25];
                    LOAD25(gx, G[t2][c]);
#pragma unroll
                    for (int u = 0; u < 25; ++u) accB[u] = fmaf(gx[u], av, accB[u]);
                }
            }
        }
    }
    // combine S partial (LDS tree in G, then global atomics)
    __syncthreads();
    float* Sl = &G[0][0][0];
    for (int e = tid; e < 640; e += 256) Sl[e] = 0.f;
    __syncthreads();
    if (tid < 200) {
#pragma unroll
        for (int u = 0; u < 25; ++u) atomicAdd(&Sl[u * 25 + vB], accB[u]);
    }
    __syncthreads();
    float* sg = ws + OFF_SG + (size_t)(n * 8 + h) * 625;
    for (int e = tid; e < 625; e += 256) atomicAdd(&sg[e], Sl[e]);
    // RU/RV partials from Rs
    if (tid < 50) {
        int u = tid % 25;
        const float* mw = ws + ((tid < 25) ? OFF_MK : OFF_MQ) + h * 64;
        float s = 0.f;
        for (int c = 0; c < 64; ++c) s = fmaf(mw[c], Rs[c][u], s);
        size_t dst = ((tid < 25) ? OFF_RU : OFF_RV) + (size_t)(n * 8 + h) * 25 + u;
        atomicAdd(&ws[dst], s);
    }
}

// ---------------------------------------------------------------------------
// probs = tanh(16*(S + RU[u] + RV[v] + 128*s0))*alpha + att0s
// ---------------------------------------------------------------------------
__global__ void k_probs(const float* __restrict__ alphas, const float* __restrict__ att0s,
                        float* __restrict__ ws) {
    int i = blockIdx.x * 256 + threadIdx.x;   // 160000
    int nh = i / 625, uv = i % 625;
    int h = nh & 7, u = uv / 25, v = uv % 25;
    float s = ws[OFF_SG + i] + ws[OFF_RU + nh * 25 + u] + ws[OFF_RV + nh * 25 + v]
            + 128.f * ws[OFF_S0 + h];
    ws[OFF_PROBS + i] = tanhf(16.f * s) * alphas[h] + att0s[h * 625 + uv];
}

// ---------------------------------------------------------------------------
// Fused attn-out + spatial conv + BN1 stats. Block = (n, t-chunk of 4).
// att[o,t,u] = sum_v (P_h·xs + zb_h)[o,t,v] * probs_h[u,v]  (Z in registers)
// LDS 48.7 KB -> 3 blocks/CU.
// ---------------------------------------------------------------------------
__global__ __launch_bounds__(256) void k_att(const float* __restrict__ bao,
                                             const float* __restrict__ bsp,
                                             float* __restrict__ y1,
                                             float* __restrict__ ws) {
    __shared__ float XS[4][64][28];   // xs tile; AT after h-loop
    __shared__ float WT[64][64];      // [c][o]
    __shared__ float PRT[25][28];     // [v][u]
    __shared__ float red[2][4][64];
    int nb = blockIdx.x;              // 1024 = 32n x 32tc
    int n = nb >> 5, tc = nb & 31;
    int tid = threadIdx.x;
    int o = tid & 63, tl = tid >> 6;
    const float4* xs4 = (const float4*)(ws + OFF_XS + (size_t)n * 64 * 3200);
    for (int e4 = tid; e4 < 1600; e4 += 256) {
        int c = e4 / 25, q = e4 % 25;
        float4 fv = xs4[c * 800 + tc * 25 + q];
        int jj = q * 4;
        XS[jj / 25][c][jj % 25] = fv.x;
        XS[(jj + 1) / 25][c][(jj + 1) % 25] = fv.y;
        XS[(jj + 2) / 25][c][(jj + 2) % 25] = fv.z;
        XS[(jj + 3) / 25][c][(jj + 3) % 25] = fv.w;
    }
    const float* pg = ws + OFF_PROBS + (size_t)n * 8 * 625;
    float acc[25];
    float bv = bao[o];
#pragma unroll
    for (int u = 0; u < 25; ++u) acc[u] = bv;

    for (int h = 0; h < 8; ++h) {
        __syncthreads(); // prev readers of WT/PRT done (h=0: covers XS staging)
        for (int e = tid; e < 4096; e += 256) WT[e >> 6][e & 63] = ws[OFF_P + (size_t)h * 4096 + e];
        for (int e = tid; e < 625; e += 256) PRT[e % 25][e / 25] = pg[h * 625 + e];
        __syncthreads();
        // phase 1: z[v] = zb + sum_c PT[c][o]*XS[tl][c][v]
        float z[25];
#pragma unroll
        for (int v = 0; v < 25; ++v) z[v] = 0.f;
        for (int c = 0; c < 64; ++c) {
            float w = WT[c][o];
            float gx[25];
            LOAD25(gx, XS[tl][c]);
#pragma unroll
            for (int v = 0; v < 25; ++v) z[v] = fmaf(w, gx[v], z[v]);
        }
        float zb = ws[OFF_ZB + h * 64 + o];
#pragma unroll
        for (int v = 0; v < 25; ++v) z[v] += zb;
        // phase 2: acc[u] += sum_v z[v]*PRT[v][u]
        for (int v = 0; v < 25; ++v) {
            float pr[25];
            LOAD25(pr, PRT[v]);
            float zv = z[v];
#pragma unroll
            for (int u = 0; u < 25; ++u) acc[u] = fmaf(zv, pr[u], acc[u]);
        }
    }
    __syncthreads(); // all phase-1 readers of XS done -> overwrite with AT
    STORE25(XS[tl][o], acc);

    // spatial conv 1x3 over u (zero-pad)
    float ca[25];
    float bs = bsp[o];
#pragma unroll
    for (int u = 0; u < 25; ++u) ca[u] = bs;
    for (int j = 0; j < 3; ++j) {
        __syncthreads(); // j=0: AT visible; j>0: prev-tap WT readers done
        for (int e = tid; e < 4096; e += 256) WT[e >> 6][e & 63] = ws[OFF_WSP + (size_t)j * 4096 + e];
        __syncthreads();
        for (int c = 0; c < 64; ++c) {
            float w = WT[c][o];
            float gx[25];
            LOAD25(gx, XS[tl][c]);
            if (j == 0) {
#pragma unroll
                for (int u = 1; u < 25; ++u) ca[u] = fmaf(w, gx[u - 1], ca[u]);
            } else if (j == 1) {
#pragma unroll
                for (int u = 0; u < 25; ++u) ca[u] = fmaf(w, gx[u], ca[u]);
            } else {
#pragma unroll
                for (int u = 0; u < 24; ++u) ca[u] = fmaf(w, gx[u + 1], ca[u]);
            }
        }
    }

    // BN1 partial stats
    float s1 = 0.f, s2 = 0.f;
#pragma unroll
    for (int u = 0; u < 25; ++u) { s1 += ca[u]; s2 = fmaf(ca[u], ca[u], s2); }
    red[0][tl][o] = s1;
    red[1][tl][o] = s2;
    __syncthreads();
    if (tid < 64) {
        float ss = red[0][0][tid] + red[0][1][tid] + red[0][2][tid] + red[0][3][tid];
        float sq = red[1][0][tid] + red[1][1][tid] + red[1][2][tid] + red[1][3][tid];
        atomicAdd(&ws[OFF_ST1 + tid], ss);
        atomicAdd(&ws[OFF_ST1 + 64 + tid], sq);
    }
    float* yb = y1 + (size_t)n * C_ * TV + (size_t)o * TV + (size_t)(tc * 4 + tl) * 25;
#pragma unroll
    for (int u = 0; u < 25; ++u) yb[u] = ca[u];
}

// ---------------------------------------------------------------------------
// BN coefficient kernel: a = gamma*rsqrt(var+eps), b = beta - mean*a
// ---------------------------------------------------------------------------
__global__ void k_bn(const float* __restrict__ gamma, const float* __restrict__ beta,
                     float* __restrict__ ws, size_t statoff, size_t aboff) {
    int c = threadIdx.x;
    if (c < 64) {
        float s = ws[statoff + c], sq = ws[statoff + 64 + c];
        float mean = s / NTV;
        float var = sq / NTV - mean * mean;
        float a = gamma[c] / sqrtf(var + 1e-5f);
        ws[aboff + c] = a;
        ws[aboff + 64 + c] = beta[c] - mean * a;
    }
}

// ---------------------------------------------------------------------------
// Temporal conv (5x1 over T) on xs2 = relu(a1*y1+b1+x), + BN2 stats.
// Block = (n, t-chunk of 4), xs2 tile (t-halo 2) in [8][64][28] LDS.
// LDS 74.5 KB -> 2 blocks/CU.
// ---------------------------------------------------------------------------
__global__ __launch_bounds__(256) void k_time(const float* __restrict__ x,
                                              const float* __restrict__ y1,
                                              const float* __restrict__ bt,
                                              float* __restrict__ ws) {
    __shared__ float XS[8][64][28];   // slices t0-2 .. t0+5
    __shared__ float WT[64][64];
    __shared__ float ab[128];
    __shared__ float red[2][4][64];
    int nb = blockIdx.x;
    int n = nb >> 5;
    int t0 = (nb & 31) * 4;
    int tid = threadIdx.x;
    if (tid < 128) ab[tid] = ws[OFF_AB1 + tid];
    __syncthreads();
    const float* xb = x + (size_t)n * C_ * TV;
    const float* yb = y1 + (size_t)n * C_ * TV;
    for (int e = tid; e < 12800; e += 256) {
        int c = e / 200, s = e % 200;
        int tt = t0 - 2 + s / 25;
        float val = 0.f;
        if (tt >= 0 && tt < 128) {
            size_t idx = (size_t)c * TV + tt * 25 + (s % 25);
            val = fmaxf(fmaf(ab[c], yb[idx], ab[64 + c]) + xb[idx], 0.f);
        }
        XS[s / 25][c][s % 25] = val;
    }
    int o = tid & 63;
    int tl = tid >> 6;
    float acc[25];
    float bv = bt[o];
#pragma unroll
    for (int u = 0; u < 25; ++u) acc[u] = bv;
    for (int kt = 0; kt < 5; ++kt) {
        __syncthreads(); // kt=0: staging done; kt>0: prev-tap WT readers done
        for (int e = tid; e < 4096; e += 256) WT[e >> 6][e & 63] = ws[OFF_WT + (size_t)kt * 4096 + e];
        __syncthreads();
        for (int c = 0; c < 64; ++c) {
            float w = WT[c][o];
            float gx[25];
            LOAD25(gx, XS[tl + kt][c]);
#pragma unroll
            for (int u = 0; u < 25; ++u) acc[u] = fmaf(w, gx[u], acc[u]);
        }
    }
    float s1 = 0.f, s2 = 0.f;
#pragma unroll
    for (int u = 0; u < 25; ++u) { s1 += acc[u]; s2 = fmaf(acc[u], acc[u], s2); }
    red[0][tl][o] = s1;
    red[1][tl][o] = s2;
    __syncthreads();
    if (tid < 64) {
        float ss = red[0][0][tid] + red[0][1][tid] + red[0][2][tid] + red[0][3][tid];
        float sq = red[1][0][tid] + red[1][1][tid] + red[1][2][tid] + red[1][3][tid];
        atomicAdd(&ws[OFF_ST2 + tid], ss);
        atomicAdd(&ws[OFF_ST2 + 64 + tid], sq);
    }
    float* y2b = ws + OFF_Y2 + (size_t)n * C_ * TV + (size_t)o * TV + (size_t)(t0 + tl) * 25;
#pragma unroll
    for (int u = 0; u < 25; ++u) y2b[u] = acc[u];
}

// ---------------------------------------------------------------------------
// Final: out = relu(a2*y2 + b2 + x), float4-vectorized
// ---------------------------------------------------------------------------
__global__ void k_final(const float* __restrict__ x, const float* __restrict__ ws,
                        float* __restrict__ out) {
    int i = blockIdx.x * 256 + threadIdx.x;
    if (i < 1638400) {
        const float4* y4 = (const float4*)(ws + OFF_Y2);
        const float4* x4 = (const float4*)x;
        float4 y = y4[i], xx = x4[i];
        int c = (i / 800) & 63;
        float a = ws[OFF_AB2 + c], b = ws[OFF_AB2 + 64 + c];
        float4 r;
        r.x = fmaxf(fmaf(a, y.x, b) + xx.x, 0.f);
        r.y = fmaxf(fmaf(a, y.y, b) + xx.y, 0.f);
        r.z = fmaxf(fmaf(a, y.z, b) + xx.z, 0.f);
        r.w = fmaxf(fmaf(a, y.w, b) + xx.w, 0.f);
        ((float4*)out)[i] = r;
    }
}

extern "C" void kernel_launch(void* const* d_in, const int* in_sizes, int n_in,
                              void* d_out, int out_size, void* d_ws, size_t ws_size,
                              hipStream_t stream) {
    const float* x      = (const float*)d_in[0];
    const float* Wqkv   = (const float*)d_in[1];
    const float* bqkv   = (const float*)d_in[2];
    const float* alphas = (const float*)d_in[3];
    const float* att0s  = (const float*)d_in[4];
    const float* Wao    = (const float*)d_in[5];
    const float* bao    = (const float*)d_in[6];
    const float* Wsp    = (const float*)d_in[7];
    const float* bsp    = (const float*)d_in[8];
    const float* Wt     = (const float*)d_in[9];
    const float* bt     = (const float*)d_in[10];
    const float* gamma  = (const float*)d_in[11];
    const float* beta   = (const float*)d_in[12];
    float* out = (float*)d_out;
    float* ws  = (float*)d_ws;
    float* y1  = out; // park pre-BN1 conv output in d_out; overwritten by k_final

    // zero accumulators (SG+RU+RV contiguous; ST1+ST2 contiguous)
    hipMemsetAsync((char*)d_ws + OFF_SG * 4, 0, (160000 + 6400 + 6400) * 4, stream);
    hipMemsetAsync((char*)d_ws + OFF_ST1 * 4, 0, 256 * 4, stream);

    k_xs    <<<dim3(6400), dim3(256), 0, stream>>>(x, ws);
    k_setup <<<dim3(391),  dim3(256), 0, stream>>>(Wqkv, bqkv, Wao, Wsp, Wt, ws);
    k_scores<<<dim3(1024), dim3(256), 0, stream>>>(ws);
    k_probs <<<dim3(625),  dim3(256), 0, stream>>>(alphas, att0s, ws);
    k_att   <<<dim3(1024), dim3(256), 0, stream>>>(bao, bsp, y1, ws);
    k_bn    <<<dim3(1),    dim3(64),  0, stream>>>(gamma, beta, ws, OFF_ST1, OFF_AB1);
    k_time  <<<dim3(1024), dim3(256), 0, stream>>>(x, y1, bt, ws);
    k_bn    <<<dim3(1),    dim3(64),  0, stream>>>(gamma, beta, ws, OFF_ST2, OFF_AB2);
    k_final <<<dim3(6400), dim3(256), 0, stream>>>(x, ws, out);
}

// Round 10
// 690.695 us; speedup vs baseline: 2.5961x; 1.2170x over previous
//
#include <hip/hip_runtime.h>
#include <hip/hip_bf16.h>
#include <math.h>

// Problem constants
constexpr int N_  = 32;
constexpr int C_  = 64;
constexpr int T_  = 128;
constexpr int V_  = 25;
constexpr int TV  = T_ * V_;         // 3200
constexpr float NTV = 102400.0f;     // 32*128*25

// Workspace layout (float offsets)
constexpr size_t OFF_MT    = 0;        // 8*64*64  MtT[h][c][cp] = (Wk^T Wq)[cp][c]
constexpr size_t OFF_P     = 32768;    // 8*64*64  PT[h][c][o]  = (Wao_h Wv_h)[o][c]
constexpr size_t OFF_ZB    = 65536;    // 8*64     Wao_h bv_h
constexpr size_t OFF_MK    = 66048;    // 8*64     Wk^T bq
constexpr size_t OFF_MQ    = 66560;    // 8*64     Wq^T bk
constexpr size_t OFF_S0    = 67072;    // 8 (pad 64)
constexpr size_t OFF_WSP   = 67136;    // 3*64*64  WspT[tap][c][o]
constexpr size_t OFF_WT    = 79424;    // 5*64*64  WtT[kt][c][o]
constexpr size_t OFF_SG    = 99904;    // 256*625  partial scores
constexpr size_t OFF_RU    = 259904;   // 256*25
constexpr size_t OFF_RV    = 266304;   // 256*25
constexpr size_t OFF_PROBS = 272704;   // 256*625
constexpr size_t OFF_ST1   = 432704;   // 128 (sum, sumsq)
constexpr size_t OFF_ST2   = 432832;   // 128
constexpr size_t OFF_AB1   = 432960;   // 128 (a, b)
constexpr size_t OFF_AB2   = 433088;   // 128
constexpr size_t OFF_XS    = 433216;   // 6,553,600 (x+pe; later reused as Y2)
constexpr size_t OFF_Y2    = OFF_XS;

// Load 25 consecutive floats from a 16B-aligned base via float4
#define LOAD25(dst, base)                                                     \
  { const float4* _p4 = (const float4*)(base);                                \
    float4 _a = _p4[0], _b = _p4[1], _c = _p4[2], _d = _p4[3], _e = _p4[4],   \
           _f = _p4[5];                                                       \
    dst[0]=_a.x; dst[1]=_a.y; dst[2]=_a.z; dst[3]=_a.w;                       \
    dst[4]=_b.x; dst[5]=_b.y; dst[6]=_b.z; dst[7]=_b.w;                       \
    dst[8]=_c.x; dst[9]=_c.y; dst[10]=_c.z; dst[11]=_c.w;                     \
    dst[12]=_d.x; dst[13]=_d.y; dst[14]=_d.z; dst[15]=_d.w;                   \
    dst[16]=_e.x; dst[17]=_e.y; dst[18]=_e.z; dst[19]=_e.w;                   \
    dst[20]=_f.x; dst[21]=_f.y; dst[22]=_f.z; dst[23]=_f.w;                   \
    dst[24]=((const float*)(base))[24]; }

#define STORE25(base, src)                                                    \
  { float4* _p4 = (float4*)(base);                                           \
    _p4[0] = make_float4(src[0],src[1],src[2],src[3]);                        \
    _p4[1] = make_float4(src[4],src[5],src[6],src[7]);                        \
    _p4[2] = make_float4(src[8],src[9],src[10],src[11]);                      \
    _p4[3] = make_float4(src[12],src[13],src[14],src[15]);                    \
    _p4[4] = make_float4(src[16],src[17],src[18],src[19]);                    \
    _p4[5] = make_float4(src[20],src[21],src[22],src[23]);                    \
    ((float*)(base))[24] = src[24]; }

// ---------------------------------------------------------------------------
// XS = x + pos_embed, float4-vectorized, fast trig
// ---------------------------------------------------------------------------
__global__ void k_xs(const float* __restrict__ x, float* __restrict__ ws) {
    int i4 = blockIdx.x * 256 + threadIdx.x;        // over 1,638,400 float4s
    int row = i4 / 800;                              // n*64 + c
    int q = i4 % 800;
    int c = row & 63;
    int r0 = q * 4;                                  // pos index t*25+v
    float f = __expf(-(float)(2 * (c >> 1)) * 0.14391156816875288f); // ln(1e4)/64
    float4 xv = ((const float4*)x)[i4];
    float a0 = r0 * f, a1 = (r0 + 1) * f, a2 = (r0 + 2) * f, a3 = (r0 + 3) * f;
    float4 r;
    if (c & 1) {
        r.x = xv.x + __cosf(a0); r.y = xv.y + __cosf(a1);
        r.z = xv.z + __cosf(a2); r.w = xv.w + __cosf(a3);
    } else {
        r.x = xv.x + __sinf(a0); r.y = xv.y + __sinf(a1);
        r.z = xv.z + __sinf(a2); r.w = xv.w + __sinf(a3);
    }
    ((float4*)(ws + OFF_XS))[i4] = r;
}

// ---------------------------------------------------------------------------
// Setup: folded weight products (pre-transposed for coalesced reads)
// ---------------------------------------------------------------------------
__global__ void k_setup(const float* __restrict__ Wqkv, const float* __restrict__ bqkv,
                        const float* __restrict__ Wao, const float* __restrict__ Wsp,
                        const float* __restrict__ Wt, float* __restrict__ ws) {
    int i = blockIdx.x * 256 + threadIdx.x;
    if (i < 32768) { // MtT[h][c][cp] = sum_dd Wk[dd,cp]*Wq[dd,c]
        int h = i >> 12, c = (i >> 6) & 63, cp = i & 63;
        const float* wk = Wqkv + (size_t)(512 + h * 64) * 64;
        const float* wq = Wqkv + (size_t)(h * 64) * 64;
        float s = 0.f;
        for (int dd = 0; dd < 64; ++dd) s = fmaf(wk[dd * 64 + cp], wq[dd * 64 + c], s);
        ws[OFF_MT + i] = s;
        return;
    }
    int j = i - 32768;
    if (j < 32768) { // PT[h][c][o] = sum_dd Wao[o, h*64+dd]*Wv[dd,c]
        int h = j >> 12, c = (j >> 6) & 63, o = j & 63;
        const float* wa = Wao + (size_t)o * 512 + h * 64;
        const float* wv = Wqkv + (size_t)(1024 + h * 64) * 64;
        float s = 0.f;
        for (int dd = 0; dd < 64; ++dd) s = fmaf(wa[dd], wv[dd * 64 + c], s);
        ws[OFF_P + j] = s;
        return;
    }
    j -= 32768;
    if (j < 512) { // zb[h][o]
        int h = j >> 6, o = j & 63;
        float s = 0.f;
        for (int dd = 0; dd < 64; ++dd)
            s = fmaf(Wao[(size_t)o * 512 + h * 64 + dd], bqkv[1024 + h * 64 + dd], s);
        ws[OFF_ZB + j] = s;
        return;
    }
    j -= 512;
    if (j < 512) { // mk[h][cp]
        int h = j >> 6, cp = j & 63;
        float s = 0.f;
        for (int dd = 0; dd < 64; ++dd)
            s = fmaf(Wqkv[(size_t)(512 + h * 64 + dd) * 64 + cp], bqkv[h * 64 + dd], s);
        ws[OFF_MK + j] = s;
        return;
    }
    j -= 512;
    if (j < 512) { // mq[h][c]
        int h = j >> 6, c = j & 63;
        float s = 0.f;
        for (int dd = 0; dd < 64; ++dd)
            s = fmaf(Wqkv[(size_t)(h * 64 + dd) * 64 + c], bqkv[512 + h * 64 + dd], s);
        ws[OFF_MQ + j] = s;
        return;
    }
    j -= 512;
    if (j < 8) { // s0[h] = bq_h . bk_h
        float s = 0.f;
        for (int dd = 0; dd < 64; ++dd) s = fmaf(bqkv[j * 64 + dd], bqkv[512 + j * 64 + dd], s);
        ws[OFF_S0 + j] = s;
        return;
    }
    j -= 8;
    if (j < 12288) { // WspT[tap][c][o]
        int tap = j >> 12, rest = j & 4095, c = rest >> 6, o = rest & 63;
        ws[OFF_WSP + j] = Wsp[(size_t)o * 192 + c * 3 + tap];
        return;
    }
    j -= 12288;
    if (j < 20480) { // WtT[kt][c][o]
        int kt = j >> 12, rest = j & 4095, c = rest >> 6, o = rest & 63;
        ws[OFF_WT + j] = Wt[(size_t)o * 320 + c * 5 + kt];
        return;
    }
}

// ---------------------------------------------------------------------------
// Scores partials. Block = (n, h, t-quarter). Phase A: 2 cp/thread, c-split-2,
// Mt read from global (L1). Phase B unchanged. LDS 63.7 KB -> 2 blocks/CU.
// ---------------------------------------------------------------------------
__global__ __launch_bounds__(256, 2) void k_scores(float* __restrict__ ws) {
    __shared__ float G[4][64][28];    // [tt][c][v]
    __shared__ float A[4][64][28];
    __shared__ float Rs[64][25];
    int nb = blockIdx.x;              // 1024 = 32n x 8h x 4tq
    int n = nb >> 5, h = (nb >> 2) & 7, tq = nb & 3;
    int tid = threadIdx.x;
    for (int e = tid; e < 1600; e += 256) Rs[e / 25][e % 25] = 0.f;
    const float4* xs4 = (const float4*)(ws + OFF_XS + (size_t)n * 64 * 3200);
    int cpg = tid & 31, cp0 = cpg * 2;        // phase-A output pair
    int cs = (tid >> 5) & 1;                  // c-half
    int tt = tid >> 6;                        // 0..3
    int vB = tid % 25, c0B = (tid / 25) * 8;  // phase-B role (tid < 200)
    const float2* mt2 = (const float2*)(ws + OFF_MT + (size_t)h * 4096);
    float accB[25];
#pragma unroll
    for (int u = 0; u < 25; ++u) accB[u] = 0.f;

    for (int ch = 0; ch < 8; ++ch) {
        int t0 = tq * 32 + ch * 4;
        __syncthreads(); // prev phase-B readers of G/A done
        for (int e4 = tid; e4 < 1600; e4 += 256) {
            int c = e4 / 25, q = e4 % 25;
            float4 fv = xs4[c * 800 + ((t0 * 25) >> 2) + q];
            int jj = q * 4;
            G[jj / 25][c][jj % 25] = fv.x;
            G[(jj + 1) / 25][c][(jj + 1) % 25] = fv.y;
            G[(jj + 2) / 25][c][(jj + 2) % 25] = fv.z;
            G[(jj + 3) / 25][c][(jj + 3) % 25] = fv.w;
        }
        __syncthreads();
        for (int e = tid; e < 1600; e += 256) {
            int c = e / 25, v = e % 25;
            Rs[c][v] += G[0][c][v] + G[1][c][v] + G[2][c][v] + G[3][c][v];
        }
        // phase A partial: a[i][v] = sum_{c in half} Mt[c][cp0+i]*G[tt][c][v]
        float a0[25], a1[25];
#pragma unroll
        for (int v = 0; v < 25; ++v) { a0[v] = 0.f; a1[v] = 0.f; }
        for (int ci = 0; ci < 32; ++ci) {
            int c = cs * 32 + ci;
            float2 m = mt2[c * 32 + cpg];
            float gx[25];
            LOAD25(gx, G[tt][c]);
#pragma unroll
            for (int v = 0; v < 25; ++v) {
                a0[v] = fmaf(m.x, gx[v], a0[v]);
                a1[v] = fmaf(m.y, gx[v], a1[v]);
            }
        }
        if (cs == 1) { STORE25(A[tt][cp0], a0); STORE25(A[tt][cp0 + 1], a1); }
        __syncthreads();
        if (cs == 0) {
            float p0[25], p1[25];
            LOAD25(p0, A[tt][cp0]);
            LOAD25(p1, A[tt][cp0 + 1]);
#pragma unroll
            for (int v = 0; v < 25; ++v) { a0[v] += p0[v]; a1[v] += p1[v]; }
            STORE25(A[tt][cp0], a0);
            STORE25(A[tt][cp0 + 1], a1);
        }
        __syncthreads();
        // phase B: accB[u] += sum_{c in slice, tt} G[tt][c][u]*A[tt][c][vB]
        if (tid < 200) {
            for (int ci = 0; ci < 8; ++ci) {
                int c = c0B + ci;
#pragma unroll
                for (int t2 = 0; t2 < 4; ++t2) {
                    float av = A[t2][c][vB];
                    float gx[25];
                    LOAD25(gx, G[t2][c]);
#pragma unroll
                    for (int u = 0; u < 25; ++u) accB[u] = fmaf(gx[u], av, accB[u]);
                }
            }
        }
    }
    // combine S partial (LDS tree in G, then global atomics)
    __syncthreads();
    float* Sl = &G[0][0][0];
    for (int e = tid; e < 640; e += 256) Sl[e] = 0.f;
    __syncthreads();
    if (tid < 200) {
#pragma unroll
        for (int u = 0; u < 25; ++u) atomicAdd(&Sl[u * 25 + vB], accB[u]);
    }
    __syncthreads();
    float* sg = ws + OFF_SG + (size_t)(n * 8 + h) * 625;
    for (int e = tid; e < 625; e += 256) atomicAdd(&sg[e], Sl[e]);
    // RU/RV partials from Rs
    if (tid < 50) {
        int u = tid % 25;
        const float* mw = ws + ((tid < 25) ? OFF_MK : OFF_MQ) + h * 64;
        float s = 0.f;
        for (int c = 0; c < 64; ++c) s = fmaf(mw[c], Rs[c][u], s);
        size_t dst = ((tid < 25) ? OFF_RU : OFF_RV) + (size_t)(n * 8 + h) * 25 + u;
        atomicAdd(&ws[dst], s);
    }
}

// ---------------------------------------------------------------------------
// probs = tanh(16*(S + RU[u] + RV[v] + 128*s0))*alpha + att0s
// ---------------------------------------------------------------------------
__global__ void k_probs(const float* __restrict__ alphas, const float* __restrict__ att0s,
                        float* __restrict__ ws) {
    int i = blockIdx.x * 256 + threadIdx.x;   // 160000
    int nh = i / 625, uv = i % 625;
    int h = nh & 7, u = uv / 25, v = uv % 25;
    float s = ws[OFF_SG + i] + ws[OFF_RU + nh * 25 + u] + ws[OFF_RV + nh * 25 + v]
            + 128.f * ws[OFF_S0 + h];
    ws[OFF_PROBS + i] = tanhf(16.f * s) * alphas[h] + att0s[h * 625 + uv];
}

// ---------------------------------------------------------------------------
// Fused attn-out + spatial conv + BN1 stats. Block = (n, t-chunk of 8).
// 2 o-channels/thread; weights from global (L1); XS/PRT broadcast from LDS.
// LDS 64.2 KB -> 2 blocks/CU.
// ---------------------------------------------------------------------------
__global__ __launch_bounds__(256, 2) void k_att(const float* __restrict__ bao,
                                                const float* __restrict__ bsp,
                                                float* __restrict__ y1,
                                                float* __restrict__ ws) {
    __shared__ float XS[8][64][28];   // xs tile; AT after h-loop
    __shared__ float PRT[25][28];     // [v][u]
    __shared__ float red[2][8][64];
    int nb = blockIdx.x;              // 512 = 32n x 16tc
    int n = nb >> 4, tc = nb & 15;
    int tid = threadIdx.x;
    int og = tid & 31, o0 = og * 2;   // 2 output channels per thread
    int tl = tid >> 5;                // 0..7 local t
    const float4* xs4 = (const float4*)(ws + OFF_XS + (size_t)n * 64 * 3200);
    for (int e4 = tid; e4 < 3200; e4 += 256) {
        int c = e4 / 50, q = e4 % 50;
        float4 fv = xs4[c * 800 + tc * 50 + q];
        int jj = q * 4;
        XS[jj / 25][c][jj % 25] = fv.x;
        XS[(jj + 1) / 25][c][(jj + 1) % 25] = fv.y;
        XS[(jj + 2) / 25][c][(jj + 2) % 25] = fv.z;
        XS[(jj + 3) / 25][c][(jj + 3) % 25] = fv.w;
    }
    const float* pg = ws + OFF_PROBS + (size_t)n * 8 * 625;
    float acc0[25], acc1[25];
    float b0 = bao[o0], b1 = bao[o0 + 1];
#pragma unroll
    for (int u = 0; u < 25; ++u) { acc0[u] = b0; acc1[u] = b1; }

    for (int h = 0; h < 8; ++h) {
        __syncthreads(); // prev PRT readers done (h=0: covers XS staging)
        for (int e = tid; e < 625; e += 256) PRT[e % 25][e / 25] = pg[h * 625 + e];
        __syncthreads();
        // phase 1: z[i][v] = zb + sum_c PT[c][o0+i]*XS[tl][c][v]
        float z0[25], z1[25];
#pragma unroll
        for (int v = 0; v < 25; ++v) { z0[v] = 0.f; z1[v] = 0.f; }
        const float2* pt2 = (const float2*)(ws + OFF_P + (size_t)h * 4096);
        for (int c = 0; c < 64; ++c) {
            float2 w = pt2[c * 32 + og];
            float gx[25];
            LOAD25(gx, XS[tl][c]);
#pragma unroll
            for (int v = 0; v < 25; ++v) {
                z0[v] = fmaf(w.x, gx[v], z0[v]);
                z1[v] = fmaf(w.y, gx[v], z1[v]);
            }
        }
        float2 zb = ((const float2*)(ws + OFF_ZB + h * 64))[og];
#pragma unroll
        for (int v = 0; v < 25; ++v) { z0[v] += zb.x; z1[v] += zb.y; }
        // phase 2: acc[i][u] += sum_v z[i][v]*PRT[v][u]
        for (int v = 0; v < 25; ++v) {
            float pr[25];
            LOAD25(pr, PRT[v]);
            float zv0 = z0[v], zv1 = z1[v];
#pragma unroll
            for (int u = 0; u < 25; ++u) {
                acc0[u] = fmaf(zv0, pr[u], acc0[u]);
                acc1[u] = fmaf(zv1, pr[u], acc1[u]);
            }
        }
    }
    __syncthreads(); // all phase-1 readers of XS done -> overwrite with AT
    STORE25(XS[tl][o0], acc0);
    STORE25(XS[tl][o0 + 1], acc1);
    __syncthreads();

    // spatial conv 1x3 over u (zero-pad), weights from global
    float ca0[25], ca1[25];
    float s0 = bsp[o0], s1_ = bsp[o0 + 1];
#pragma unroll
    for (int u = 0; u < 25; ++u) { ca0[u] = s0; ca1[u] = s1_; }
    for (int j = 0; j < 3; ++j) {
        const float2* wsp2 = (const float2*)(ws + OFF_WSP + (size_t)j * 4096);
        for (int c2 = 0; c2 < 64; ++c2) {
            float2 w = wsp2[c2 * 32 + og];
            float gx[25];
            LOAD25(gx, XS[tl][c2]);
            if (j == 0) {
#pragma unroll
                for (int u = 1; u < 25; ++u) {
                    ca0[u] = fmaf(w.x, gx[u - 1], ca0[u]);
                    ca1[u] = fmaf(w.y, gx[u - 1], ca1[u]);
                }
            } else if (j == 1) {
#pragma unroll
                for (int u = 0; u < 25; ++u) {
                    ca0[u] = fmaf(w.x, gx[u], ca0[u]);
                    ca1[u] = fmaf(w.y, gx[u], ca1[u]);
                }
            } else {
#pragma unroll
                for (int u = 0; u < 24; ++u) {
                    ca0[u] = fmaf(w.x, gx[u + 1], ca0[u]);
                    ca1[u] = fmaf(w.y, gx[u + 1], ca1[u]);
                }
            }
        }
    }

    // BN1 partial stats
    float p1 = 0.f, p2 = 0.f, q1 = 0.f, q2 = 0.f;
#pragma unroll
    for (int u = 0; u < 25; ++u) {
        p1 += ca0[u]; p2 = fmaf(ca0[u], ca0[u], p2);
        q1 += ca1[u]; q2 = fmaf(ca1[u], ca1[u], q2);
    }
    red[0][tl][o0] = p1; red[0][tl][o0 + 1] = q1;
    red[1][tl][o0] = p2; red[1][tl][o0 + 1] = q2;
    __syncthreads();
    if (tid < 64) {
        float ss = 0.f, sq = 0.f;
        for (int t2 = 0; t2 < 8; ++t2) { ss += red[0][t2][tid]; sq += red[1][t2][tid]; }
        atomicAdd(&ws[OFF_ST1 + tid], ss);
        atomicAdd(&ws[OFF_ST1 + 64 + tid], sq);
    }
    float* yb = y1 + (size_t)n * C_ * TV + (size_t)o0 * TV + (size_t)(tc * 8 + tl) * 25;
#pragma unroll
    for (int u = 0; u < 25; ++u) { yb[u] = ca0[u]; yb[TV + u] = ca1[u]; }
}

// ---------------------------------------------------------------------------
// BN coefficient kernel
// ---------------------------------------------------------------------------
__global__ void k_bn(const float* __restrict__ gamma, const float* __restrict__ beta,
                     float* __restrict__ ws, size_t statoff, size_t aboff) {
    int c = threadIdx.x;
    if (c < 64) {
        float s = ws[statoff + c], sq = ws[statoff + 64 + c];
        float mean = s / NTV;
        float var = sq / NTV - mean * mean;
        float a = gamma[c] / sqrtf(var + 1e-5f);
        ws[aboff + c] = a;
        ws[aboff + 64 + c] = beta[c] - mean * a;
    }
}

// ---------------------------------------------------------------------------
// Temporal conv (5x1) on xs2 = relu(a1*y1+b1+x), + BN2 stats.
// 2 o/thread, c-split-2, WT from global; combine via LDS aliased over XS.
// LDS 60 KB -> 2 blocks/CU.
// ---------------------------------------------------------------------------
__global__ __launch_bounds__(256, 2) void k_time(const float* __restrict__ x,
                                                 const float* __restrict__ y1,
                                                 const float* __restrict__ bt,
                                                 float* __restrict__ ws) {
    __shared__ float XS[8][64][28];   // slices t0-2 .. t0+5; combine buf after
    __shared__ float ab[128];
    __shared__ float red[2][4][64];
    int nb = blockIdx.x;              // 1024 = 32n x 32tchunk
    int n = nb >> 5;
    int t0 = (nb & 31) * 4;
    int tid = threadIdx.x;
    int og = tid & 31, o0 = og * 2;
    int tl = (tid >> 5) & 3;
    int cs = tid >> 7;                // c-half
    if (tid < 128) ab[tid] = ws[OFF_AB1 + tid];
    __syncthreads();
    const float* xb = x + (size_t)n * C_ * TV;
    const float* yb = y1 + (size_t)n * C_ * TV;
    for (int e = tid; e < 12800; e += 256) {
        int c = e / 200, s = e % 200;
        int tt = t0 - 2 + s / 25;
        float val = 0.f;
        if (tt >= 0 && tt < 128) {
            size_t idx = (size_t)c * TV + tt * 25 + (s % 25);
            val = fmaxf(fmaf(ab[c], yb[idx], ab[64 + c]) + xb[idx], 0.f);
        }
        XS[s / 25][c][s % 25] = val;
    }
    float a0[25], a1[25];
    float b0 = bt[o0], b1 = bt[o0 + 1];
#pragma unroll
    for (int u = 0; u < 25; ++u) { a0[u] = b0; a1[u] = b1; }
    __syncthreads();
    for (int kt = 0; kt < 5; ++kt) {
        const float2* wt2 = (const float2*)(ws + OFF_WT + (size_t)kt * 4096);
        for (int ci = 0; ci < 32; ++ci) {
            int c = cs * 32 + ci;
            float2 w = wt2[c * 32 + og];
            float gx[25];
            LOAD25(gx, XS[tl + kt][c]);
#pragma unroll
            for (int u = 0; u < 25; ++u) {
                a0[u] = fmaf(w.x, gx[u], a0[u]);
                a1[u] = fmaf(w.y, gx[u], a1[u]);
            }
        }
    }
    __syncthreads(); // all XS reads done -> reuse as combine buffer
    float* comb = &XS[0][0][0];
    int slot = tid & 127;
    if (cs == 1) { STORE25(comb + slot * 56, a0); STORE25(comb + slot * 56 + 28, a1); }
    __syncthreads();
    if (cs == 0) {
        float p0[25], p1v[25];
        LOAD25(p0, comb + slot * 56);
        LOAD25(p1v, comb + slot * 56 + 28);
#pragma unroll
        for (int u = 0; u < 25; ++u) { a0[u] += p0[u]; a1[u] += p1v[u]; }
        float s1 = 0.f, s2 = 0.f, t1 = 0.f, t2v = 0.f;
#pragma unroll
        for (int u = 0; u < 25; ++u) {
            s1 += a0[u]; s2 = fmaf(a0[u], a0[u], s2);
            t1 += a1[u]; t2v = fmaf(a1[u], a1[u], t2v);
        }
        red[0][tl][o0] = s1; red[0][tl][o0 + 1] = t1;
        red[1][tl][o0] = s2; red[1][tl][o0 + 1] = t2v;
    }
    __syncthreads();
    if (tid < 64) {
        float ss = red[0][0][tid] + red[0][1][tid] + red[0][2][tid] + red[0][3][tid];
        float sq = red[1][0][tid] + red[1][1][tid] + red[1][2][tid] + red[1][3][tid];
        atomicAdd(&ws[OFF_ST2 + tid], ss);
        atomicAdd(&ws[OFF_ST2 + 64 + tid], sq);
    }
    if (cs == 0) {
        float* y2b = ws + OFF_Y2 + (size_t)n * C_ * TV + (size_t)o0 * TV + (size_t)(t0 + tl) * 25;
#pragma unroll
        for (int u = 0; u < 25; ++u) { y2b[u] = a0[u]; y2b[TV + u] = a1[u]; }
    }
}

// ---------------------------------------------------------------------------
// Final: out = relu(a2*y2 + b2 + x), float4-vectorized
// ---------------------------------------------------------------------------
__global__ void k_final(const float* __restrict__ x, const float* __restrict__ ws,
                        float* __restrict__ out) {
    int i = blockIdx.x * 256 + threadIdx.x;
    if (i < 1638400) {
        const float4* y4 = (const float4*)(ws + OFF_Y2);
        const float4* x4 = (const float4*)x;
        float4 y = y4[i], xx = x4[i];
        int c = (i / 800) & 63;
        float a = ws[OFF_AB2 + c], b = ws[OFF_AB2 + 64 + c];
        float4 r;
        r.x = fmaxf(fmaf(a, y.x, b) + xx.x, 0.f);
        r.y = fmaxf(fmaf(a, y.y, b) + xx.y, 0.f);
        r.z = fmaxf(fmaf(a, y.z, b) + xx.z, 0.f);
        r.w = fmaxf(fmaf(a, y.w, b) + xx.w, 0.f);
        ((float4*)out)[i] = r;
    }
}

extern "C" void kernel_launch(void* const* d_in, const int* in_sizes, int n_in,
                              void* d_out, int out_size, void* d_ws, size_t ws_size,
                              hipStream_t stream) {
    const float* x      = (const float*)d_in[0];
    const float* Wqkv   = (const float*)d_in[1];
    const float* bqkv   = (const float*)d_in[2];
    const float* alphas = (const float*)d_in[3];
    const float* att0s  = (const float*)d_in[4];
    const float* Wao    = (const float*)d_in[5];
    const float* bao    = (const float*)d_in[6];
    const float* Wsp    = (const float*)d_in[7];
    const float* bsp    = (const float*)d_in[8];
    const float* Wt     = (const float*)d_in[9];
    const float* bt     = (const float*)d_in[10];
    const float* gamma  = (const float*)d_in[11];
    const float* beta   = (const float*)d_in[12];
    float* out = (float*)d_out;
    float* ws  = (float*)d_ws;
    float* y1  = out; // park pre-BN1 conv output in d_out; overwritten by k_final

    // zero accumulators (SG+RU+RV contiguous; ST1+ST2 contiguous)
    hipMemsetAsync((char*)d_ws + OFF_SG * 4, 0, (160000 + 6400 + 6400) * 4, stream);
    hipMemsetAsync((char*)d_ws + OFF_ST1 * 4, 0, 256 * 4, stream);

    k_xs    <<<dim3(6400), dim3(256), 0, stream>>>(x, ws);
    k_setup <<<dim3(391),  dim3(256), 0, stream>>>(Wqkv, bqkv, Wao, Wsp, Wt, ws);
    k_scores<<<dim3(1024), dim3(256), 0, stream>>>(ws);
    k_probs <<<dim3(625),  dim3(256), 0, stream>>>(alphas, att0s, ws);
    k_att   <<<dim3(512),  dim3(256), 0, stream>>>(bao, bsp, y1, ws);
    k_bn    <<<dim3(1),    dim3(64),  0, stream>>>(gamma, beta, ws, OFF_ST1, OFF_AB1);
    k_time  <<<dim3(1024), dim3(256), 0, stream>>>(x, y1, bt, ws);
    k_bn    <<<dim3(1),    dim3(64),  0, stream>>>(gamma, beta, ws, OFF_ST2, OFF_AB2);
    k_final <<<dim3(6400), dim3(256), 0, stream>>>(x, ws, out);
}